// Round 6
// baseline (829.687 us; speedup 1.0000x reference)
//
#include <hip/hip_runtime.h>
#include <hip/hip_bf16.h>
#include <stdint.h>

#define LL 1024
#define BB 256
#define CC 96
#define HH 768
#define NW 9216   // CC*CC
#define NTOT 9408 // NW + 2*CC

typedef __attribute__((ext_vector_type(4))) float floatx4;
typedef __attribute__((ext_vector_type(2))) float floatx2;
typedef __attribute__((ext_vector_type(8))) short short8;

#define KAPPA 0x1p-16f
#define NEG_LOG_KAPPA 11.090354888959125f  // 16*ln2

__device__ __forceinline__ unsigned short f2bf(float f) {
  uint32_t u = __float_as_uint(f);
  return (unsigned short)((u + 0x7FFFu + ((u >> 16) & 1u)) >> 16);
}

// ---------------- fused bf16 MFMA GEMM: out = hidden @ [Wt;Ws;We]^T + bias ---
#define GA_LD 40  // ushort row stride: 80 B -> 2-way-max LDS conflicts (free)

__global__ __launch_bounds__(256) void gemm_mfma(
    const float* __restrict__ hidden, const float* __restrict__ Wt,
    const float* __restrict__ Ws, const float* __restrict__ We,
    const float* __restrict__ bt, const float* __restrict__ bs,
    const float* __restrict__ be, float* __restrict__ trans,
    float* __restrict__ tstart, float* __restrict__ tend) {
  __shared__ __align__(16) unsigned short As[128 * GA_LD];
  __shared__ __align__(16) unsigned short Bs[128 * GA_LD];
  const int t = threadIdx.x;
  const int lane = t & 63, wid = t >> 6;
  const int wm = wid >> 1, wn = wid & 1;
  const int l15 = lane & 15, qd = lane >> 4;
  const int m0 = blockIdx.y * 128, n0 = blockIdx.x * 128;
  const int srow = t >> 1, shalf = t & 1;

  floatx4 acc[4][4];
#pragma unroll
  for (int i = 0; i < 4; ++i)
#pragma unroll
    for (int j = 0; j < 4; ++j) acc[i][j] = (floatx4){0.f, 0.f, 0.f, 0.f};

  const int r = n0 + srow;
  const float* bsrc = (r < NW)        ? Wt + (size_t)r * HH
                      : (r < NW + CC) ? Ws + (size_t)(r - NW) * HH
                      : (r < NTOT)    ? We + (size_t)(r - NW - CC) * HH
                                      : nullptr;
  const float* asrc = hidden + (size_t)(m0 + srow) * HH;
  const int sidx = srow * GA_LD + shalf * 16;

  for (int k0 = 0; k0 < HH; k0 += 32) {
    __syncthreads();
    {  // stage A (fp32 -> bf16)
      const float4* s4 = (const float4*)(asrc + k0 + shalf * 16);
      uint32_t w[8];
#pragma unroll
      for (int u = 0; u < 4; ++u) {
        float4 v = s4[u];
        w[2 * u] = (uint32_t)f2bf(v.x) | ((uint32_t)f2bf(v.y) << 16);
        w[2 * u + 1] = (uint32_t)f2bf(v.z) | ((uint32_t)f2bf(v.w) << 16);
      }
      *(uint4*)&As[sidx] = make_uint4(w[0], w[1], w[2], w[3]);
      *(uint4*)&As[sidx + 8] = make_uint4(w[4], w[5], w[6], w[7]);
    }
    {  // stage B (fused row source)
      uint32_t w[8];
      if (bsrc) {
        const float4* s4 = (const float4*)(bsrc + k0 + shalf * 16);
#pragma unroll
        for (int u = 0; u < 4; ++u) {
          float4 v = s4[u];
          w[2 * u] = (uint32_t)f2bf(v.x) | ((uint32_t)f2bf(v.y) << 16);
          w[2 * u + 1] = (uint32_t)f2bf(v.z) | ((uint32_t)f2bf(v.w) << 16);
        }
      } else {
#pragma unroll
        for (int u = 0; u < 8; ++u) w[u] = 0u;
      }
      *(uint4*)&Bs[sidx] = make_uint4(w[0], w[1], w[2], w[3]);
      *(uint4*)&Bs[sidx + 8] = make_uint4(w[4], w[5], w[6], w[7]);
    }
    __syncthreads();
    short8 af[4], bf[4];
#pragma unroll
    for (int i = 0; i < 4; ++i)
      af[i] = *(const short8*)&As[(64 * wm + 16 * i + l15) * GA_LD + qd * 8];
#pragma unroll
    for (int j = 0; j < 4; ++j)
      bf[j] = *(const short8*)&Bs[(64 * wn + 16 * j + l15) * GA_LD + qd * 8];
#pragma unroll
    for (int i = 0; i < 4; ++i)
#pragma unroll
      for (int j = 0; j < 4; ++j)
        acc[i][j] = __builtin_amdgcn_mfma_f32_16x16x32_bf16(af[i], bf[j],
                                                            acc[i][j], 0, 0, 0);
  }

#pragma unroll
  for (int j = 0; j < 4; ++j) {
    int n = n0 + 64 * wn + 16 * j + l15;
    if (n >= NTOT) continue;
    float bv;
    float* dst;
    int ldo;
    if (n < NW) {
      bv = bt[n]; dst = trans + n; ldo = NW;
    } else if (n < NW + CC) {
      bv = bs[n - NW]; dst = tstart + (n - NW); ldo = CC;
    } else {
      bv = be[n - NW - CC]; dst = tend + (n - NW - CC); ldo = CC;
    }
#pragma unroll
    for (int i = 0; i < 4; ++i)
#pragma unroll
      for (int rr = 0; rr < 4; ++rr) {
        int m = m0 + 64 * wm + 16 * i + 4 * qd + rr;
        dst[(size_t)m * ldo] = acc[i][j][rr] + bv;
      }
  }
}

// ------- CRF scan v6: single wave, FULL dot per lane, zero cross-lane -------
// Lane l<48 owns outputs {2l, 2l+1}: T columns in 192 VGPRs (one wave/SIMD ->
// full 512-reg file). Chain: broadcast u-read -> 96 pk_fma -> E-mul -> write.
#define CHUNK 8

__device__ __forceinline__ float wredf(float v) {
#pragma unroll
  for (int m = 32; m >= 1; m >>= 1) v += __shfl_xor(v, m);
  return v;
}
__device__ __forceinline__ int wredi(int v) {
#pragma unroll
  for (int m = 32; m >= 1; m >>= 1) v += __shfl_xor(v, m);
  return v;
}
__device__ __forceinline__ float bcast0(float x) {
  return __uint_as_float(__builtin_amdgcn_readfirstlane(__float_as_uint(x)));
}

__global__ __launch_bounds__(64, 1) void crf_scan(
    const float* __restrict__ emit, const int* __restrict__ target,
    const void* __restrict__ mask, const float* __restrict__ trans,
    const float* __restrict__ tstart, const float* __restrict__ tend,
    float* __restrict__ out) {
  const int b = blockIdx.x;
  const int l = threadIdx.x;
  const bool own = l < 48;

  __shared__ __align__(16) float u_lds[CC];
  __shared__ __align__(16) float ebuf[2][CHUNK][CC];

  // ---- sequence length from mask (dtype sniffed at runtime) ----
  int cnt = 0;
  {
    unsigned w0 = *(const unsigned*)mask;
    if (w0 == 1u) {
      const int* m32 = (const int*)mask;
      for (int i = l; i < LL; i += 64) cnt += (m32[i * BB + b] != 0);
    } else if (w0 == 0x01010101u) {
      const unsigned char* m8 = (const unsigned char*)mask;
      for (int i = l; i < LL; i += 64) cnt += (m8[i * BB + b] != 0);
    } else {
      const float* mf = (const float*)mask;
      for (int i = l; i < LL; i += 64) cnt += (mf[i * BB + b] != 0.f);
    }
  }
  const int len = wredi(cnt);

  // ---- T2[j] = (expT[j][2l], expT[j][2l+1]) -- full columns in registers ----
  const float* tb = trans + (size_t)b * (CC * CC);
  floatx2 T2[96];
  {
    const int c0 = own ? 2 * l : 0;
#pragma unroll
    for (int j = 0; j < 96; ++j) {
      const float* row = tb + j * CC + c0;
      T2[j] = (floatx2){__expf(row[0]), __expf(row[1])};
    }
  }

  // ---- emit chunk pipeline: 64 lanes stage 8x96 floats per chunk ----
  int idx0[3], rowA[3], c4A[3];
#pragma unroll
  for (int u = 0; u < 3; ++u) {
    int v = l + 64 * u;
    rowA[u] = v / 24;
    c4A[u] = v - 24 * rowA[u];
    idx0[u] = (rowA[u] * BB + b) * 24 + c4A[u];
  }
  const float4* e4 = (const float4*)emit;
  float4 rr[3];
#pragma unroll
  for (int u = 0; u < 3; ++u) {  // chunk 0 -> LDS
    float4 v = e4[idx0[u]];
    floatx4 o = {__expf(v.x) * KAPPA, __expf(v.y) * KAPPA,
                 __expf(v.z) * KAPPA, __expf(v.w) * KAPPA};
    *(floatx4*)&ebuf[0][rowA[u]][c4A[u] * 4] = o;
  }
#pragma unroll
  for (int u = 0; u < 3; ++u) rr[u] = e4[idx0[u] + CHUNK * (BB * 24)];  // chunk 1

  // ---- init: u0 = exp(a0 - a0[0]), L = a0[0] ----
  float a00 = emit[(size_t)b * CC] + tstart[b * CC];
  float L = a00;
  {
    float v = emit[(size_t)b * CC + l] + tstart[b * CC + l];
    u_lds[l] = __expf(v - a00);
    if (l < 32) {
      int c2 = l + 64;
      float v2 = emit[(size_t)b * CC + c2] + tstart[b * CC + c2];
      u_lds[c2] = __expf(v2 - a00);
    }
  }
  asm volatile("" ::: "memory");  // in-wave DS in-order: no barrier needed

  const int eoff = own ? 2 * l : 0;
  float pv = 1.0f;  // u[0] carried one step ahead (readfirstlane, off-chain)

  // ---- main recurrence: zero barriers, zero cross-lane on the chain ----
  for (int i = 1; i < len; ++i) {
    if ((i & (CHUNK - 1)) == 0) {  // stage next chunk
      int ch = i >> 3;
      int es = ch & 1;
#pragma unroll
      for (int u = 0; u < 3; ++u) {
        float4 v = rr[u];
        floatx4 o = {__expf(v.x) * KAPPA, __expf(v.y) * KAPPA,
                     __expf(v.z) * KAPPA, __expf(v.w) * KAPPA};
        *(floatx4*)&ebuf[es][rowA[u]][c4A[u] * 4] = o;
      }
      int nb = (ch + 1) * CHUNK;
      if (nb < LL) {
#pragma unroll
        for (int u = 0; u < 3; ++u) rr[u] = e4[idx0[u] + nb * (BB * 24)];
      }
      asm volatile("" ::: "memory");
    }
    float invP = 1.0f;
    if ((i & 3) == 0) {  // renorm with pivot captured last step (off-chain)
      invP = 1.0f / pv;
      L += __logf(pv);
    }
    const floatx4* up = (const floatx4*)u_lds;  // broadcast reads
    floatx2 ac0 = {0.f, 0.f}, ac1 = {0.f, 0.f};
    floatx2 ac2 = {0.f, 0.f}, ac3 = {0.f, 0.f};
#pragma unroll
    for (int j4 = 0; j4 < 24; ++j4) {
      floatx4 U = up[j4];
      ac0 += T2[4 * j4 + 0] * U.x;
      ac1 += T2[4 * j4 + 1] * U.y;
      ac2 += T2[4 * j4 + 2] * U.z;
      ac3 += T2[4 * j4 + 3] * U.w;
    }
    floatx2 a = (ac0 + ac1) + (ac2 + ac3);
    floatx2 E = *(const floatx2*)&ebuf[(i >> 3) & 1][i & (CHUNK - 1)][eoff];
    floatx2 nw = a * E * invP;
    if (((i + 1) & 3) == 0) pv = bcast0(nw.x);  // pivot for next step's renorm
    if (own) *(floatx2*)&u_lds[2 * l] = nw;
    asm volatile("" ::: "memory");
  }

  // ---- log Z (wave reduction; slow shfl OK once) ----
  float zp;
  {
    zp = u_lds[l] * __expf(tend[b * CC + l]);
    if (l < 32) {
      int c2 = l + 64;
      zp += u_lds[c2] * __expf(tend[b * CC + c2]);
    }
  }
  float zsum = wredf(zp);
  float logz = L + (float)(len - 1) * NEG_LOG_KAPPA + __logf(zsum);

  // ---- gold-path score ----
  float sc = 0.f;
  for (int i = l; i < len; i += 64) {
    int tg = target[i * BB + b];
    sc += emit[((size_t)i * BB + b) * CC + tg];
    if (i >= 1) {
      int tp = target[(i - 1) * BB + b];
      sc += tb[tp * CC + tg];
    }
  }
  float score = wredf(sc);
  if (l == 0) {
    int tg0 = target[b];
    int tgl = target[(len - 1) * BB + b];
    score += tstart[b * CC + tg0] + tend[b * CC + tgl];
    atomicAdd(out, (logz - score) * (1.0f / 256.0f));
  }
}

extern "C" void kernel_launch(void* const* d_in, const int* in_sizes, int n_in,
                              void* d_out, int out_size, void* d_ws, size_t ws_size,
                              hipStream_t stream) {
  const float* emit = (const float*)d_in[0];
  const float* hidden = (const float*)d_in[1];
  const int* target = (const int*)d_in[2];
  const void* mask = d_in[3];
  const float* Wt = (const float*)d_in[4];
  const float* bt = (const float*)d_in[5];
  const float* Ws = (const float*)d_in[6];
  const float* bs = (const float*)d_in[7];
  const float* We = (const float*)d_in[8];
  const float* be = (const float*)d_in[9];

  float* trans_ws = (float*)d_ws;                  // 256*9216
  float* ts_ws = trans_ws + (size_t)BB * CC * CC;  // 256*96
  float* te_ws = ts_ws + (size_t)BB * CC;          // 256*96

  hipMemsetAsync(d_out, 0, sizeof(float), stream);

  gemm_mfma<<<dim3((NTOT + 127) / 128, 2), 256, 0, stream>>>(
      hidden, Wt, Ws, We, bt, bs, be, trans_ws, ts_ws, te_ws);

  crf_scan<<<BB, 64, 0, stream>>>(emit, target, mask, trans_ws, ts_ws, te_ws,
                                  (float*)d_out);
}

// Round 7
// 390.050 us; speedup vs baseline: 2.1271x; 2.1271x over previous
//
#include <hip/hip_runtime.h>
#include <hip/hip_bf16.h>
#include <stdint.h>

#define LL 1024
#define BB 256
#define CC 96
#define HH 768
#define NW 9216   // CC*CC
#define NTOT 9408 // NW + 2*CC
#define SEGS 4
#define SEGLEN 256
#define CHPB 7    // chains per batch: 4 fw + 3 bw

typedef __attribute__((ext_vector_type(4))) float floatx4;
typedef __attribute__((ext_vector_type(2))) float floatx2;
typedef __attribute__((ext_vector_type(8))) short short8;

#define KAPPA 0x1p-16f
#define NEG_LOG_KAPPA 11.090354888959125f  // 16*ln2

__device__ __forceinline__ unsigned short f2bf(float f) {
  uint32_t u = __float_as_uint(f);
  return (unsigned short)((u + 0x7FFFu + ((u >> 16) & 1u)) >> 16);
}

// ---------------- fused bf16 MFMA GEMM: out = hidden @ [Wt;Ws;We]^T + bias ---
#define GA_LD 40

__global__ __launch_bounds__(256) void gemm_mfma(
    const float* __restrict__ hidden, const float* __restrict__ Wt,
    const float* __restrict__ Ws, const float* __restrict__ We,
    const float* __restrict__ bt, const float* __restrict__ bs,
    const float* __restrict__ be, float* __restrict__ trans,
    float* __restrict__ tstart, float* __restrict__ tend) {
  __shared__ __align__(16) unsigned short As[128 * GA_LD];
  __shared__ __align__(16) unsigned short Bs[128 * GA_LD];
  const int t = threadIdx.x;
  const int lane = t & 63, wid = t >> 6;
  const int wm = wid >> 1, wn = wid & 1;
  const int l15 = lane & 15, qd = lane >> 4;
  const int m0 = blockIdx.y * 128, n0 = blockIdx.x * 128;
  const int srow = t >> 1, shalf = t & 1;

  floatx4 acc[4][4];
#pragma unroll
  for (int i = 0; i < 4; ++i)
#pragma unroll
    for (int j = 0; j < 4; ++j) acc[i][j] = (floatx4){0.f, 0.f, 0.f, 0.f};

  const int r = n0 + srow;
  const float* bsrc = (r < NW)        ? Wt + (size_t)r * HH
                      : (r < NW + CC) ? Ws + (size_t)(r - NW) * HH
                      : (r < NTOT)    ? We + (size_t)(r - NW - CC) * HH
                                      : nullptr;
  const float* asrc = hidden + (size_t)(m0 + srow) * HH;
  const int sidx = srow * GA_LD + shalf * 16;

  for (int k0 = 0; k0 < HH; k0 += 32) {
    __syncthreads();
    {
      const float4* s4 = (const float4*)(asrc + k0 + shalf * 16);
      uint32_t w[8];
#pragma unroll
      for (int u = 0; u < 4; ++u) {
        float4 v = s4[u];
        w[2 * u] = (uint32_t)f2bf(v.x) | ((uint32_t)f2bf(v.y) << 16);
        w[2 * u + 1] = (uint32_t)f2bf(v.z) | ((uint32_t)f2bf(v.w) << 16);
      }
      *(uint4*)&As[sidx] = make_uint4(w[0], w[1], w[2], w[3]);
      *(uint4*)&As[sidx + 8] = make_uint4(w[4], w[5], w[6], w[7]);
    }
    {
      uint32_t w[8];
      if (bsrc) {
        const float4* s4 = (const float4*)(bsrc + k0 + shalf * 16);
#pragma unroll
        for (int u = 0; u < 4; ++u) {
          float4 v = s4[u];
          w[2 * u] = (uint32_t)f2bf(v.x) | ((uint32_t)f2bf(v.y) << 16);
          w[2 * u + 1] = (uint32_t)f2bf(v.z) | ((uint32_t)f2bf(v.w) << 16);
        }
      } else {
#pragma unroll
        for (int u = 0; u < 8; ++u) w[u] = 0u;
      }
      *(uint4*)&Bs[sidx] = make_uint4(w[0], w[1], w[2], w[3]);
      *(uint4*)&Bs[sidx + 8] = make_uint4(w[4], w[5], w[6], w[7]);
    }
    __syncthreads();
    short8 af[4], bf[4];
#pragma unroll
    for (int i = 0; i < 4; ++i)
      af[i] = *(const short8*)&As[(64 * wm + 16 * i + l15) * GA_LD + qd * 8];
#pragma unroll
    for (int j = 0; j < 4; ++j)
      bf[j] = *(const short8*)&Bs[(64 * wn + 16 * j + l15) * GA_LD + qd * 8];
#pragma unroll
    for (int i = 0; i < 4; ++i)
#pragma unroll
      for (int j = 0; j < 4; ++j)
        acc[i][j] = __builtin_amdgcn_mfma_f32_16x16x32_bf16(af[i], bf[j],
                                                            acc[i][j], 0, 0, 0);
  }

#pragma unroll
  for (int j = 0; j < 4; ++j) {
    int n = n0 + 64 * wn + 16 * j + l15;
    if (n >= NTOT) continue;
    float bv;
    float* dst;
    int ldo;
    if (n < NW) {
      bv = bt[n]; dst = trans + n; ldo = NW;
    } else if (n < NW + CC) {
      bv = bs[n - NW]; dst = tstart + (n - NW); ldo = CC;
    } else {
      bv = be[n - NW - CC]; dst = tend + (n - NW - CC); ldo = CC;
    }
#pragma unroll
    for (int i = 0; i < 4; ++i)
#pragma unroll
      for (int rr = 0; rr < 4; ++rr) {
        int m = m0 + 64 * wm + 16 * i + 4 * qd + rr;
        dst[(size_t)m * ldo] = acc[i][j][rr] + bv;
      }
  }
}

// ---------------- helpers --------------------------------------------------
__device__ __forceinline__ float wredf(float v) {
#pragma unroll
  for (int m = 32; m >= 1; m >>= 1) v += __shfl_xor(v, m);
  return v;
}
__device__ __forceinline__ int wredi(int v) {
#pragma unroll
  for (int m = 32; m >= 1; m >>= 1) v += __shfl_xor(v, m);
  return v;
}
__device__ __forceinline__ float bcast0(float x) {
  return __uint_as_float(__builtin_amdgcn_readfirstlane(__float_as_uint(x)));
}
__device__ __forceinline__ int get_len(const void* mask, int b, int l) {
  int cnt = 0;
  unsigned w0 = *(const unsigned*)mask;
  if (w0 == 1u) {
    const int* m32 = (const int*)mask;
    for (int i = l; i < LL; i += 64) cnt += (m32[i * BB + b] != 0);
  } else if (w0 == 0x01010101u) {
    const unsigned char* m8 = (const unsigned char*)mask;
    for (int i = l; i < LL; i += 64) cnt += (m8[i * BB + b] != 0);
  } else {
    const float* mf = (const float*)mask;
    for (int i = l; i < LL; i += 64) cnt += (mf[i * BB + b] != 0.f);
  }
  return wredi(cnt);
}

// ---------------- segment chain kernel: 1792 blocks x 1 wave ----------------
// cid = b*7 + k. k<4: forward segment k (seg0 starts from true u0, else 1s).
// k>=4: backward segment k-3 (left Perron direction of that segment).
__global__ __launch_bounds__(64, 2) void crf_chain(
    const float* __restrict__ emit, const void* __restrict__ mask,
    const float* __restrict__ trans, const float* __restrict__ tstart,
    float* __restrict__ xvec, float* __restrict__ lsc) {
  const int cid = blockIdx.x;
  const int b = cid / CHPB;
  const int k = cid - CHPB * b;
  const bool isfw = (k < SEGS);
  const int seg = isfw ? k : (k - (SEGS - 1));
  const int l = threadIdx.x;
  const int pr = l >> 1, s = l & 1;

  __shared__ __align__(16) float ebuf[2][8][CC];  // exp(emit)*kappa ring
  __shared__ __align__(16) float u_lds[CC];       // (placed after ebuf: E overread lands here)

  const int len = get_len(mask, b, l);
  const int lo = seg * SEGLEN + 1;
  const int hi = min((seg + 1) * SEGLEN, len - 1);
  float* xout = xvec + (size_t)cid * CC;
  if (hi < lo) {  // empty segment -> identity; composition skips it
    xout[l] = 1.f;
    if (l < 32) xout[l + 64] = 1.f;
    if (l == 0) lsc[cid] = 0.f;
    return;
  }
  const int n = hi - lo + 1;

  // ---- T registers: fw = columns slice (R5 layout); bw = rows slice ----
  const float* tb = trans + (size_t)b * (CC * CC);
  floatx2 T2[3][24];
  if (isfw) {
#pragma unroll
    for (int j = 0; j < 24; ++j) {
      const float* r0 = tb + (48 * s + 2 * j) * CC + 3 * pr;
      const float* r1 = r0 + CC;
#pragma unroll
      for (int o = 0; o < 3; ++o)
        T2[o][j] = (floatx2){__expf(r0[o]), __expf(r1[o])};
    }
  } else {
#pragma unroll
    for (int o = 0; o < 3; ++o) {
      const float* row = tb + (3 * pr + o) * CC + 48 * s;
#pragma unroll
      for (int j = 0; j < 24; ++j)
        T2[o][j] = (floatx2){__expf(row[2 * j]), __expf(row[2 * j + 1])};
    }
  }

  // ---- emit staging geometry: 64 lanes stage 8x96 floats per chunk ----
  int rowA[3], c4A[3];
#pragma unroll
  for (int u = 0; u < 3; ++u) {
    int v = l + 64 * u;
    rowA[u] = v / 24;
    c4A[u] = v - 24 * rowA[u];
  }
  const float4* e4 = (const float4*)emit;
  float4 rr[3];
  const int eoff = 3 * pr + 2 * s;
  float L = 0.f, pv = 1.f;

#define STAGE_CHUNK(baserow, slot)                                        \
  {                                                                       \
    _Pragma("unroll") for (int u = 0; u < 3; ++u) {                       \
      float4 v = e4[(((baserow) + rowA[u]) * BB + b) * 24 + c4A[u]];      \
      floatx4 o = {__expf(v.x) * KAPPA, __expf(v.y) * KAPPA,              \
                   __expf(v.z) * KAPPA, __expf(v.w) * KAPPA};             \
      *(floatx4*)&ebuf[slot][rowA[u]][c4A[u] * 4] = o;                    \
    }                                                                     \
  }
#define PREFETCH_CHUNK(baserow)                                           \
  {                                                                       \
    _Pragma("unroll") for (int u = 0; u < 3; ++u)                         \
        rr[u] = e4[(((baserow) + rowA[u]) * BB + b) * 24 + c4A[u]];       \
  }
#define COMMIT_CHUNK(slot)                                                \
  {                                                                       \
    _Pragma("unroll") for (int u = 0; u < 3; ++u) {                       \
      float4 v = rr[u];                                                   \
      floatx4 o = {__expf(v.x) * KAPPA, __expf(v.y) * KAPPA,              \
                   __expf(v.z) * KAPPA, __expf(v.w) * KAPPA};             \
      *(floatx4*)&ebuf[slot][rowA[u]][c4A[u] * 4] = o;                    \
    }                                                                     \
  }

#define INNER_DOT(a0, a1, a2)                                             \
  float a0, a1, a2;                                                       \
  {                                                                       \
    const floatx4* up = (const floatx4*)&u_lds[48 * s];                   \
    floatx2 A0 = {0.f, 0.f}, B0 = {0.f, 0.f};                             \
    floatx2 A1 = {0.f, 0.f}, B1 = {0.f, 0.f};                             \
    floatx2 A2 = {0.f, 0.f}, B2 = {0.f, 0.f};                             \
    _Pragma("unroll") for (int j4 = 0; j4 < 12; ++j4) {                   \
      floatx4 U = up[j4];                                                 \
      floatx2 lo2 = {U.x, U.y}, hi2 = {U.z, U.w};                         \
      A0 += lo2 * T2[0][2 * j4]; B0 += hi2 * T2[0][2 * j4 + 1];           \
      A1 += lo2 * T2[1][2 * j4]; B1 += hi2 * T2[1][2 * j4 + 1];           \
      A2 += lo2 * T2[2][2 * j4]; B2 += hi2 * T2[2][2 * j4 + 1];           \
    }                                                                     \
    floatx2 S0 = A0 + B0, S1 = A1 + B1, S2 = A2 + B2;                     \
    a0 = S0.x + S0.y; a1 = S1.x + S1.y; a2 = S2.x + S2.y;                 \
    a0 += __shfl_xor(a0, 1);                                              \
    a1 += __shfl_xor(a1, 1);                                              \
    a2 += __shfl_xor(a2, 1);                                              \
  }

  if (isfw) {
    const int base0 = lo & ~7;
    STAGE_CHUNK(base0, (base0 >> 3) & 1);
    if (base0 + 8 < LL) PREFETCH_CHUNK(base0 + 8);
    if (seg == 0) {
      float a00 = emit[(size_t)b * CC] + tstart[b * CC];
      L = a00;
      float v = emit[(size_t)b * CC + l] + tstart[b * CC + l];
      u_lds[l] = __expf(v - a00);
      if (l < 32) {
        int c2 = l + 64;
        float v2 = emit[(size_t)b * CC + c2] + tstart[b * CC + c2];
        u_lds[c2] = __expf(v2 - a00);
      }
    } else {
      u_lds[l] = 1.f;
      if (l < 32) u_lds[l + 64] = 1.f;
    }
    asm volatile("" ::: "memory");
    int jj = 1;
    for (int i = lo; i <= hi; ++i, ++jj) {
      if ((i & 7) == 0) {
        COMMIT_CHUNK((i >> 3) & 1);
        int nb = i + 8;
        if (nb < LL) PREFETCH_CHUNK(nb);
        asm volatile("" ::: "memory");
      }
      float invP = 1.f;
      if ((jj & 3) == 0) { invP = 1.0f / pv; L += __logf(pv); }
      INNER_DOT(a0, a1, a2);
      floatx2 E = *(const floatx2*)&ebuf[(i >> 3) & 1][i & 7][eoff];
      float o0 = a0 * E.x * invP;
      if (((jj + 1) & 3) == 0) pv = bcast0(o0);
      if (s == 0) {
        floatx2 wv = {o0, a1 * E.y * invP};
        *(floatx2*)&u_lds[3 * pr] = wv;
      } else {
        u_lds[3 * pr + 2] = a2 * E.x * invP;
      }
      asm volatile("" ::: "memory");
    }
  } else {
    const int cb = hi & ~7;
    STAGE_CHUNK(cb, (cb >> 3) & 1);
    if (cb - 8 >= 0) PREFETCH_CHUNK(cb - 8);
    asm volatile("" ::: "memory");
    // init w = E_hi * kappa (already staged)
    u_lds[l] = ebuf[(hi >> 3) & 1][hi & 7][l];
    if (l < 32) u_lds[l + 64] = ebuf[(hi >> 3) & 1][hi & 7][l + 64];
    asm volatile("" ::: "memory");
    int jj = 1;
    for (int i = hi; i >= lo; --i, ++jj) {
      if ((i & 7) == 0 && i > lo) {  // row i-1 crosses into lower chunk
        COMMIT_CHUNK(((i >> 3) & 1) ^ 1);
        int nb = i - 16;
        if (nb >= 0) PREFETCH_CHUNK(nb);
        asm volatile("" ::: "memory");
      }
      float invP = 1.f;
      if ((jj & 3) == 0) { invP = 1.0f / pv; L += __logf(pv); }
      INNER_DOT(a0, a1, a2);
      floatx2 E = (i > lo)
          ? *(const floatx2*)&ebuf[((i - 1) >> 3) & 1][(i - 1) & 7][eoff]
          : (floatx2){1.f, 1.f};
      float o0 = a0 * E.x * invP;
      if (((jj + 1) & 3) == 0) pv = bcast0(o0);
      if (s == 0) {
        floatx2 wv = {o0, a1 * E.y * invP};
        *(floatx2*)&u_lds[3 * pr] = wv;
      } else {
        u_lds[3 * pr + 2] = a2 * E.x * invP;
      }
      asm volatile("" ::: "memory");
    }
  }

  asm volatile("" ::: "memory");
  xout[l] = u_lds[l];
  if (l < 32) xout[l + 64] = u_lds[l + 64];
  if (l == 0) lsc[cid] = L + (float)n * NEG_LOG_KAPPA;
}

// ---------------- composition + score: 256 blocks x 1 wave ------------------
__global__ __launch_bounds__(64) void crf_compose(
    const float* __restrict__ emit, const int* __restrict__ target,
    const void* __restrict__ mask, const float* __restrict__ trans,
    const float* __restrict__ tstart, const float* __restrict__ tend,
    const float* __restrict__ xvec, const float* __restrict__ lsc,
    float* __restrict__ out) {
  const int b = blockIdx.x;
  const int l = threadIdx.x;
  const int len = get_len(mask, b, l);

  // telescope: x_s = a_s * e^{g_s} * (b_s . x_{s-1})/(b_s . 1)
  float Lam = lsc[b * CHPB + 0];
  const float* xcur = xvec + (size_t)(b * CHPB + 0) * CC;
  for (int s2 = 1; s2 < SEGS; ++s2) {
    if (s2 * SEGLEN + 1 > len - 1) break;  // empty segment = identity
    const float* bh = xvec + (size_t)(b * CHPB + (SEGS - 1) + s2) * CC;
    const float* ah = xvec + (size_t)(b * CHPB + s2) * CC;
    float pn = bh[l] * xcur[l];
    float pd = bh[l];
    if (l < 32) {
      pn += bh[l + 64] * xcur[l + 64];
      pd += bh[l + 64];
    }
    float num = wredf(pn), den = wredf(pd);
    Lam += __logf(num / den) + lsc[b * CHPB + s2];
    xcur = ah;
  }
  float zp = xcur[l] * __expf(tend[b * CC + l]);
  if (l < 32) zp += xcur[l + 64] * __expf(tend[b * CC + l + 64]);
  float logz = Lam + __logf(wredf(zp));

  // gold-path score
  const float* tb = trans + (size_t)b * (CC * CC);
  float sc = 0.f;
  for (int i = l; i < len; i += 64) {
    int tg = target[i * BB + b];
    sc += emit[((size_t)i * BB + b) * CC + tg];
    if (i >= 1) sc += tb[target[(i - 1) * BB + b] * CC + tg];
  }
  float score = wredf(sc);
  if (l == 0) {
    score += tstart[b * CC + target[b]] +
             tend[b * CC + target[(len - 1) * BB + b]];
    atomicAdd(out, (logz - score) * (1.0f / 256.0f));
  }
}

extern "C" void kernel_launch(void* const* d_in, const int* in_sizes, int n_in,
                              void* d_out, int out_size, void* d_ws, size_t ws_size,
                              hipStream_t stream) {
  const float* emit = (const float*)d_in[0];
  const float* hidden = (const float*)d_in[1];
  const int* target = (const int*)d_in[2];
  const void* mask = d_in[3];
  const float* Wt = (const float*)d_in[4];
  const float* bt = (const float*)d_in[5];
  const float* Ws = (const float*)d_in[6];
  const float* bs = (const float*)d_in[7];
  const float* We = (const float*)d_in[8];
  const float* be = (const float*)d_in[9];

  float* trans_ws = (float*)d_ws;                  // 256*9216
  float* ts_ws = trans_ws + (size_t)BB * CC * CC;  // 256*96
  float* te_ws = ts_ws + (size_t)BB * CC;          // 256*96
  float* xvec = te_ws + (size_t)BB * CC;           // 1792*96
  float* lsc = xvec + (size_t)BB * CHPB * CC;      // 1792

  hipMemsetAsync(d_out, 0, sizeof(float), stream);

  gemm_mfma<<<dim3((NTOT + 127) / 128, 2), 256, 0, stream>>>(
      hidden, Wt, Ws, We, bt, bs, be, trans_ws, ts_ws, te_ws);

  crf_chain<<<BB * CHPB, 64, 0, stream>>>(emit, mask, trans_ws, ts_ws, xvec, lsc);

  crf_compose<<<BB, 64, 0, stream>>>(emit, target, mask, trans_ws, ts_ws, te_ws,
                                     xvec, lsc, (float*)d_out);
}